// Round 1
// baseline (7384.750 us; speedup 1.0000x reference)
//
#include <hip/hip_runtime.h>
#include <math.h>

#define T_TOK 2048
#define HDIM  4096
#define QKVN  6144
#define NHEADS 32
#define HD    128
#define KV_OFF 4096
#define V_OFF  5120
#define SCALE 0.08838834764831843f

// ---------------------------------------------------------------------------
// fp32 SGEMM: C[M,N] = A[M,K] * B[K,N], all row-major.
// 128x128 block tile, BK=8, 256 threads, 8x8 micro-tile split as 4+4 rows/cols
// (offsets ty*4 and 64+ty*4) so LDS reads are broadcast / 2-way (free on gfx950).
// M, N, K all divisible by tile dims for this problem (2048, 4096/6144, 4096).
// ---------------------------------------------------------------------------
template <int N_, int K_>
__global__ __launch_bounds__(256) void sgemm(const float* __restrict__ A,
                                             const float* __restrict__ B,
                                             float* __restrict__ C) {
    __shared__ float As[8][128];
    __shared__ float Bs[8][128];

    const int tid = threadIdx.x;
    const int bm = blockIdx.y * 128;
    const int bn = blockIdx.x * 128;
    const int tx = tid & 15;   // 0..15 -> n groups
    const int ty = tid >> 4;   // 0..15 -> m groups

    // staging load indices
    const int lm  = tid >> 1;         // 0..127 : A tile row
    const int lkq = (tid & 1) * 4;    // 0 or 4 : A tile k (float4)
    const int lr  = tid >> 5;         // 0..7   : B tile row (k)
    const int lnq = (tid & 31) * 4;   // 0..124 : B tile col (float4)

    float acc[8][8];
#pragma unroll
    for (int i = 0; i < 8; i++)
#pragma unroll
        for (int j = 0; j < 8; j++) acc[i][j] = 0.f;

    const float* Aptr = A + (size_t)(bm + lm) * K_ + lkq;
    const float* Bptr = B + (size_t)lr * N_ + bn + lnq;

    for (int k0 = 0; k0 < K_; k0 += 8) {
        float4 av = *(const float4*)Aptr;
        float4 bv = *(const float4*)Bptr;
        __syncthreads();   // previous tile fully consumed
        As[lkq + 0][lm] = av.x;
        As[lkq + 1][lm] = av.y;
        As[lkq + 2][lm] = av.z;
        As[lkq + 3][lm] = av.w;
        *(float4*)&Bs[lr][lnq] = bv;
        __syncthreads();
        Aptr += 8;
        Bptr += (size_t)8 * N_;

#pragma unroll
        for (int kk = 0; kk < 8; kk++) {
            float4 a0 = *(const float4*)&As[kk][ty * 4];
            float4 a1 = *(const float4*)&As[kk][64 + ty * 4];
            float4 b0 = *(const float4*)&Bs[kk][tx * 4];
            float4 b1 = *(const float4*)&Bs[kk][64 + tx * 4];
            float a[8] = {a0.x, a0.y, a0.z, a0.w, a1.x, a1.y, a1.z, a1.w};
            float b[8] = {b0.x, b0.y, b0.z, b0.w, b1.x, b1.y, b1.z, b1.w};
#pragma unroll
            for (int i = 0; i < 8; i++)
#pragma unroll
                for (int j = 0; j < 8; j++) acc[i][j] += a[i] * b[j];
        }
    }

#pragma unroll
    for (int i = 0; i < 8; i++) {
        int row = bm + ((i < 4) ? (ty * 4 + i) : (64 + ty * 4 + i - 4));
        float4 c0 = {acc[i][0], acc[i][1], acc[i][2], acc[i][3]};
        float4 c1 = {acc[i][4], acc[i][5], acc[i][6], acc[i][7]};
        *(float4*)&C[(size_t)row * N_ + bn + tx * 4] = c0;
        *(float4*)&C[(size_t)row * N_ + bn + 64 + tx * 4] = c1;
    }
}

// ---------------------------------------------------------------------------
// NeoX RoPE applied in-place to q (heads 0..31) and k (heads 32..39) of qkv.
// grid (T, 10), block 256: each block does 4 "128-wide head slots" of one row.
// ---------------------------------------------------------------------------
__global__ __launch_bounds__(256) void rope_kernel(const int* __restrict__ pos,
                                                   float* __restrict__ qkv) {
    const int t = blockIdx.x;
    const int head = blockIdx.y * 4 + (threadIdx.x >> 6);  // 0..39
    const int d = threadIdx.x & 63;                        // 0..63
    const float p = (float)pos[t];
    const float invf = powf(1.0e6f, -(float)d * (1.0f / 64.0f));
    const float f = p * invf;
    const float c = cosf(f), s = sinf(f);
    float* base = qkv + (size_t)t * QKVN + head * HD;
    const float x1 = base[d];
    const float x2 = base[d + 64];
    base[d]      = x1 * c - x2 * s;
    base[d + 64] = x2 * c + x1 * s;
}

// ---------------------------------------------------------------------------
// Causal GQA attention, one block (256 threads) per (token t, q-head h).
// Scores staged in LDS (8KB), block max/sum reduction, 2-way-split PV pass.
// ---------------------------------------------------------------------------
__global__ __launch_bounds__(256) void attn_kernel(const float* __restrict__ qkv,
                                                   float* __restrict__ out) {
    const int t = blockIdx.x;
    const int h = blockIdx.y;
    const int kvh = h >> 2;           // 4:1 GQA
    const int tid = threadIdx.x;
    const int lane = tid & 63;
    const int wv = tid >> 6;

    __shared__ float qs[HD];
    __shared__ float w[T_TOK];
    __shared__ float red[4];
    __shared__ float pv[256];

    const float* qrow = qkv + (size_t)t * QKVN + h * HD;
    if (tid < HD) qs[tid] = qrow[tid] * SCALE;
    __syncthreads();

    const int len = t + 1;
    const float* K = qkv + KV_OFF + kvh * HD;

    float lmax = -3.4e38f;
    for (int s = tid; s < len; s += 256) {
        const float* kr = K + (size_t)s * QKVN;
        float dot = 0.f;
#pragma unroll
        for (int d4 = 0; d4 < HD; d4 += 4) {
            float4 k4 = *(const float4*)(kr + d4);
            float4 q4 = *(const float4*)(qs + d4);
            dot += q4.x * k4.x + q4.y * k4.y + q4.z * k4.z + q4.w * k4.w;
        }
        w[s] = dot;
        lmax = fmaxf(lmax, dot);
    }
#pragma unroll
    for (int off = 1; off < 64; off <<= 1)
        lmax = fmaxf(lmax, __shfl_xor(lmax, off, 64));
    if (lane == 0) red[wv] = lmax;
    __syncthreads();
    const float M = fmaxf(fmaxf(red[0], red[1]), fmaxf(red[2], red[3]));

    float lsum = 0.f;
    for (int s = tid; s < len; s += 256) {
        float e = expf(w[s] - M);
        w[s] = e;
        lsum += e;
    }
#pragma unroll
    for (int off = 1; off < 64; off <<= 1)
        lsum += __shfl_xor(lsum, off, 64);
    __syncthreads();   // red reads done + all w writes visible
    if (lane == 0) red[wv] = lsum;
    __syncthreads();
    const float inv = 1.0f / (red[0] + red[1] + red[2] + red[3]);

    // PV: thread = (dim d, parity p); coalesced V reads (lanes 0..63 contiguous)
    const float* V = qkv + V_OFF + kvh * HD;
    const int d = tid & 127;
    const int p = tid >> 7;
    float acc = 0.f;
#pragma unroll 4
    for (int s = p; s < len; s += 2) acc += w[s] * V[(size_t)s * QKVN + d];
    pv[tid] = acc;
    __syncthreads();
    if (tid < 128)
        out[(size_t)t * (NHEADS * HD) + h * HD + tid] = (pv[tid] + pv[tid + 128]) * inv;
}

// ---------------------------------------------------------------------------
extern "C" void kernel_launch(void* const* d_in, const int* in_sizes, int n_in,
                              void* d_out, int out_size, void* d_ws, size_t ws_size,
                              hipStream_t stream) {
    const int*   positions = (const int*)d_in[0];
    const float* hidden    = (const float*)d_in[1];
    const float* Wqkv      = (const float*)d_in[2];
    const float* Wo        = (const float*)d_in[3];
    float* out = (float*)d_out;

    float* qkv  = (float*)d_ws;                       // 2048 x 6144 fp32 = 50.3 MB
    float* attn = qkv + (size_t)T_TOK * QKVN;         // 2048 x 4096 fp32 = 33.6 MB

    // 1) qkv = hidden @ Wqkv
    sgemm<QKVN, HDIM><<<dim3(QKVN / 128, T_TOK / 128), 256, 0, stream>>>(hidden, Wqkv, qkv);
    // 2) RoPE on q,k portions in-place
    rope_kernel<<<dim3(T_TOK, 10), 256, 0, stream>>>(positions, qkv);
    // 3) causal GQA attention -> attn [2048, 4096]
    attn_kernel<<<dim3(T_TOK, NHEADS), 256, 0, stream>>>(qkv, attn);
    // 4) out = attn @ Wo
    sgemm<HDIM, HDIM><<<dim3(HDIM / 128, T_TOK / 128), 256, 0, stream>>>(attn, Wo, out);
}

// Round 2
// 2906.042 us; speedup vs baseline: 2.5412x; 2.5412x over previous
//
#include <hip/hip_runtime.h>
#include <math.h>

#define T_TOK 2048
#define HDIM  4096
#define QKVN  6144
#define NHEADS 32
#define HD    128
#define KV_OFF 4096
#define V_OFF  5120
#define SCALE 0.08838834764831843f

// ---------------------------------------------------------------------------
// fp32 SGEMM (unchanged from R1): ~99 TF, LDS-BW bound at 8x8 micro-tile.
// ---------------------------------------------------------------------------
template <int N_, int K_>
__global__ __launch_bounds__(256) void sgemm(const float* __restrict__ A,
                                             const float* __restrict__ B,
                                             float* __restrict__ C) {
    __shared__ float As[8][128];
    __shared__ float Bs[8][128];

    const int tid = threadIdx.x;
    const int bm = blockIdx.y * 128;
    const int bn = blockIdx.x * 128;
    const int tx = tid & 15;
    const int ty = tid >> 4;

    const int lm  = tid >> 1;
    const int lkq = (tid & 1) * 4;
    const int lr  = tid >> 5;
    const int lnq = (tid & 31) * 4;

    float acc[8][8];
#pragma unroll
    for (int i = 0; i < 8; i++)
#pragma unroll
        for (int j = 0; j < 8; j++) acc[i][j] = 0.f;

    const float* Aptr = A + (size_t)(bm + lm) * K_ + lkq;
    const float* Bptr = B + (size_t)lr * N_ + bn + lnq;

    for (int k0 = 0; k0 < K_; k0 += 8) {
        float4 av = *(const float4*)Aptr;
        float4 bv = *(const float4*)Bptr;
        __syncthreads();
        As[lkq + 0][lm] = av.x;
        As[lkq + 1][lm] = av.y;
        As[lkq + 2][lm] = av.z;
        As[lkq + 3][lm] = av.w;
        *(float4*)&Bs[lr][lnq] = bv;
        __syncthreads();
        Aptr += 8;
        Bptr += (size_t)8 * N_;

#pragma unroll
        for (int kk = 0; kk < 8; kk++) {
            float4 a0 = *(const float4*)&As[kk][ty * 4];
            float4 a1 = *(const float4*)&As[kk][64 + ty * 4];
            float4 b0 = *(const float4*)&Bs[kk][tx * 4];
            float4 b1 = *(const float4*)&Bs[kk][64 + tx * 4];
            float a[8] = {a0.x, a0.y, a0.z, a0.w, a1.x, a1.y, a1.z, a1.w};
            float b[8] = {b0.x, b0.y, b0.z, b0.w, b1.x, b1.y, b1.z, b1.w};
#pragma unroll
            for (int i = 0; i < 8; i++)
#pragma unroll
                for (int j = 0; j < 8; j++) acc[i][j] += a[i] * b[j];
        }
    }

#pragma unroll
    for (int i = 0; i < 8; i++) {
        int row = bm + ((i < 4) ? (ty * 4 + i) : (64 + ty * 4 + i - 4));
        float4 c0 = {acc[i][0], acc[i][1], acc[i][2], acc[i][3]};
        float4 c1 = {acc[i][4], acc[i][5], acc[i][6], acc[i][7]};
        *(float4*)&C[(size_t)row * N_ + bn + tx * 4] = c0;
        *(float4*)&C[(size_t)row * N_ + bn + 64 + tx * 4] = c1;
    }
}

// ---------------------------------------------------------------------------
// NeoX RoPE in-place on q (heads 0..31) and k (heads 32..39). Unchanged.
// ---------------------------------------------------------------------------
__global__ __launch_bounds__(256) void rope_kernel(const int* __restrict__ pos,
                                                   float* __restrict__ qkv) {
    const int t = blockIdx.x;
    const int head = blockIdx.y * 4 + (threadIdx.x >> 6);
    const int d = threadIdx.x & 63;
    const float p = (float)pos[t];
    const float invf = powf(1.0e6f, -(float)d * (1.0f / 64.0f));
    const float f = p * invf;
    const float c = cosf(f), s = sinf(f);
    float* base = qkv + (size_t)t * QKVN + head * HD;
    const float x1 = base[d];
    const float x2 = base[d + 64];
    base[d]      = x1 * c - x2 * s;
    base[d + 64] = x2 * c + x1 * s;
}

// ---------------------------------------------------------------------------
// Flash-style causal GQA attention (fp32).
// Block = 256 threads = one (head, 64-row Q tile). S-tiles of 32 keys.
// LDS: Qs[64][132] + KVs[32][132] (K/V union) + Ps[64][34] = 59392 B
//  -> 2 blocks/CU. Thread (tx=tid&7, ty=tid>>3):
//   score: rows q = ty+32i (i<2), cols s = tx+8j (j<4)  [b128 reads, 2-way max]
//   PV:    rows q = ty+32i,      dims d = 4tx+32jj (jj<4)
// Online softmax state (m,l,alpha) lives in registers, replicated across the
// 8 tx lanes of each row group (shfl_xor 1/2/4 reductions stay in-wave).
// ---------------------------------------------------------------------------
#define DOT4(acc, a, b) acc += (a).x*(b).x + (a).y*(b).y + (a).z*(b).z + (a).w*(b).w
#define FMA4(o, p, v) { (o).x += (p)*(v).x; (o).y += (p)*(v).y; (o).z += (p)*(v).z; (o).w += (p)*(v).w; }

__global__ __launch_bounds__(256, 2) void flash_attn(const float* __restrict__ qkv,
                                                     float* __restrict__ out) {
    __shared__ float Qs[64 * 132];
    __shared__ float KVs[32 * 132];
    __shared__ float Ps[64 * 34];

    // balanced swizzle: pair qi with 31-qi so each CU slot gets ~equal work
    const int b = blockIdx.x;             // 0..1023
    const int half = (b >> 9) & 1;
    const int rest = b & 511;
    const int h = rest >> 4;              // 0..31
    const int qlo = rest & 15;            // 0..15
    const int qi = half ? (31 - qlo) : qlo;  // 0..31
    const int kvh = h >> 2;

    const int tid = threadIdx.x;
    const int tx = tid & 7;
    const int ty = tid >> 3;              // 0..31

    // ---- stage Q tile (64 x 128), pre-scaled ----
    {
        const float* qbase = qkv + (size_t)(qi * 64) * QKVN + h * HD;
#pragma unroll
        for (int r = 0; r < 8; r++) {
            int idx = r * 256 + tid;
            int qrow = idx >> 5;
            int d = (idx & 31) * 4;
            float4 v = *(const float4*)(qbase + (size_t)qrow * QKVN + d);
            v.x *= SCALE; v.y *= SCALE; v.z *= SCALE; v.w *= SCALE;
            *(float4*)(Qs + qrow * 132 + d) = v;
        }
    }

    float m[2], l[2];
    float4 O[2][4];
#pragma unroll
    for (int i = 0; i < 2; i++) {
        m[i] = -INFINITY;
        l[i] = 0.f;
#pragma unroll
        for (int jj = 0; jj < 4; jj++) O[i][jj] = make_float4(0.f, 0.f, 0.f, 0.f);
    }

    const float* kbase = qkv + KV_OFF + kvh * HD;
    const float* vbase = qkv + V_OFF + kvh * HD;
    const int qg0 = qi * 64 + ty;         // +32*i
    const int nst = 2 * qi + 2;

    for (int st = 0; st < nst; st++) {
        __syncthreads();                  // prior PV done: KVs + Ps reusable
        // ---- stage K tile (32 x 128) ----
#pragma unroll
        for (int r = 0; r < 4; r++) {
            int idx = r * 256 + tid;
            int srow = idx >> 5;
            int d = (idx & 31) * 4;
            *(float4*)(KVs + srow * 132 + d) =
                *(const float4*)(kbase + (size_t)(st * 32 + srow) * QKVN + d);
        }
        __syncthreads();                  // K visible

        // ---- scores S[i][j] = Q[ty+32i] . K[tx+8j] ----
        float S[2][4];
#pragma unroll
        for (int i = 0; i < 2; i++)
#pragma unroll
            for (int j = 0; j < 4; j++) S[i][j] = 0.f;

#pragma unroll 4
        for (int kk = 0; kk < HD; kk += 4) {
            float4 q0 = *(const float4*)(Qs + ty * 132 + kk);
            float4 q1 = *(const float4*)(Qs + (ty + 32) * 132 + kk);
            float4 k0 = *(const float4*)(KVs + tx * 132 + kk);
            float4 k1 = *(const float4*)(KVs + (tx + 8) * 132 + kk);
            float4 k2 = *(const float4*)(KVs + (tx + 16) * 132 + kk);
            float4 k3 = *(const float4*)(KVs + (tx + 24) * 132 + kk);
            DOT4(S[0][0], q0, k0); DOT4(S[0][1], q0, k1);
            DOT4(S[0][2], q0, k2); DOT4(S[0][3], q0, k3);
            DOT4(S[1][0], q1, k0); DOT4(S[1][1], q1, k1);
            DOT4(S[1][2], q1, k2); DOT4(S[1][3], q1, k3);
        }

        // ---- causal mask + online softmax ----
        const int sg0 = st * 32 + tx;     // +8*j
        float alpha[2];
#pragma unroll
        for (int i = 0; i < 2; i++) {
            const int qg = qg0 + 32 * i;
            float rmax = -INFINITY;
#pragma unroll
            for (int j = 0; j < 4; j++) {
                if (sg0 + 8 * j > qg) S[i][j] = -INFINITY;
                rmax = fmaxf(rmax, S[i][j]);
            }
#pragma unroll
            for (int off = 1; off < 8; off <<= 1)
                rmax = fmaxf(rmax, __shfl_xor(rmax, off));
            const float mnew = fmaxf(m[i], rmax);
            alpha[i] = __expf(m[i] - mnew);
            float rsum = 0.f;
#pragma unroll
            for (int j = 0; j < 4; j++) {
                S[i][j] = __expf(S[i][j] - mnew);
                rsum += S[i][j];
            }
#pragma unroll
            for (int off = 1; off < 8; off <<= 1)
                rsum += __shfl_xor(rsum, off);
            l[i] = l[i] * alpha[i] + rsum;
            m[i] = mnew;
        }

        // ---- P -> LDS ----
#pragma unroll
        for (int i = 0; i < 2; i++)
#pragma unroll
            for (int j = 0; j < 4; j++)
                Ps[(ty + 32 * i) * 34 + tx + 8 * j] = S[i][j];

        __syncthreads();                  // K reads done + Ps visible
        // ---- stage V tile into the same buffer ----
#pragma unroll
        for (int r = 0; r < 4; r++) {
            int idx = r * 256 + tid;
            int srow = idx >> 5;
            int d = (idx & 31) * 4;
            *(float4*)(KVs + srow * 132 + d) =
                *(const float4*)(vbase + (size_t)(st * 32 + srow) * QKVN + d);
        }
        __syncthreads();                  // V visible

        // ---- O rescale + PV accumulate ----
#pragma unroll
        for (int i = 0; i < 2; i++) {
            const float a = alpha[i];
#pragma unroll
            for (int jj = 0; jj < 4; jj++) {
                O[i][jj].x *= a; O[i][jj].y *= a; O[i][jj].z *= a; O[i][jj].w *= a;
            }
        }
#pragma unroll 4
        for (int s = 0; s < 32; s++) {
            float p0 = Ps[ty * 34 + s];
            float p1 = Ps[(ty + 32) * 34 + s];
            const float* vr = KVs + s * 132 + 4 * tx;
            float4 v0 = *(const float4*)(vr);
            float4 v1 = *(const float4*)(vr + 32);
            float4 v2 = *(const float4*)(vr + 64);
            float4 v3 = *(const float4*)(vr + 96);
            FMA4(O[0][0], p0, v0); FMA4(O[0][1], p0, v1);
            FMA4(O[0][2], p0, v2); FMA4(O[0][3], p0, v3);
            FMA4(O[1][0], p1, v0); FMA4(O[1][1], p1, v1);
            FMA4(O[1][2], p1, v2); FMA4(O[1][3], p1, v3);
        }
    }

    // ---- epilogue: O / l -> out ----
#pragma unroll
    for (int i = 0; i < 2; i++) {
        const float inv = 1.0f / l[i];
        float* orow = out + (size_t)(qi * 64 + ty + 32 * i) * HDIM + h * HD + 4 * tx;
#pragma unroll
        for (int jj = 0; jj < 4; jj++) {
            float4 w = O[i][jj];
            w.x *= inv; w.y *= inv; w.z *= inv; w.w *= inv;
            *(float4*)(orow + 32 * jj) = w;
        }
    }
}

// ---------------------------------------------------------------------------
extern "C" void kernel_launch(void* const* d_in, const int* in_sizes, int n_in,
                              void* d_out, int out_size, void* d_ws, size_t ws_size,
                              hipStream_t stream) {
    const int*   positions = (const int*)d_in[0];
    const float* hidden    = (const float*)d_in[1];
    const float* Wqkv      = (const float*)d_in[2];
    const float* Wo        = (const float*)d_in[3];
    float* out = (float*)d_out;

    float* qkv  = (float*)d_ws;                   // 2048 x 6144 fp32
    float* attn = qkv + (size_t)T_TOK * QKVN;     // 2048 x 4096 fp32

    sgemm<QKVN, HDIM><<<dim3(QKVN / 128, T_TOK / 128), 256, 0, stream>>>(hidden, Wqkv, qkv);
    rope_kernel<<<dim3(T_TOK, 10), 256, 0, stream>>>(positions, qkv);
    flash_attn<<<dim3(1024), 256, 0, stream>>>(qkv, attn);
    sgemm<HDIM, HDIM><<<dim3(HDIM / 128, T_TOK / 128), 256, 0, stream>>>(attn, Wo, out);
}

// Round 3
// 1280.553 us; speedup vs baseline: 5.7668x; 2.2694x over previous
//
#include <hip/hip_runtime.h>
#include <math.h>

#define T_TOK 2048
#define HDIM  4096
#define QKVN  6144
#define NHEADS 32
#define HD    128
#define KV_OFF 4096
#define V_OFF  5120
#define SCALE 0.08838834764831843f

typedef __attribute__((ext_vector_type(8))) short short8;
typedef __attribute__((ext_vector_type(4))) float f32x4;

__device__ __forceinline__ ushort f2bf(float f) {
    union { float f; unsigned u; } v; v.f = f;
    unsigned r = v.u + 0x7FFFu + ((v.u >> 16) & 1u);   // RNE
    return (ushort)(r >> 16);
}

// ---------------------------------------------------------------------------
// bf16 MFMA GEMM (m97 structure): C[M,N] = A[M,K] * B^T[N,K], C fp32.
// 128x128 tile, BK=32, 256 thr = 4 waves in 2x2, each wave 4x4 x mfma 16x16x32.
// Staging via global_load_lds width=16 (wave-uniform base + lane*16).
// ---------------------------------------------------------------------------
template <int N_, int K_>
__global__ __launch_bounds__(256) void gemm_bf16(const ushort* __restrict__ A,
                                                 const ushort* __restrict__ B,
                                                 float* __restrict__ C) {
    __shared__ ushort As[128 * 32];
    __shared__ ushort Bs[128 * 32];

    const int tid = threadIdx.x;
    const int w = tid >> 6;
    const int l = tid & 63;
    const int bm = blockIdx.y * 128;
    const int bn = blockIdx.x * 128;
    const int wm = (w & 1) * 64;
    const int wn = (w >> 1) * 64;

    f32x4 acc[4][4];
#pragma unroll
    for (int i = 0; i < 4; i++)
#pragma unroll
        for (int j = 0; j < 4; j++) acc[i][j] = (f32x4){0.f, 0.f, 0.f, 0.f};

    // staging: pass p covers tile rows p*64 + tid/4; lane stages 16B (8 bf16)
    const ushort* ag = A + (size_t)(bm + (tid >> 2)) * K_ + (tid & 3) * 8;
    const ushort* bg = B + (size_t)(bn + (tid >> 2)) * K_ + (tid & 3) * 8;

    auto ldsA = (__attribute__((address_space(3))) char*)As;
    auto ldsB = (__attribute__((address_space(3))) char*)Bs;
    const int wb = w * 1024;

    for (int k0 = 0; k0 < K_; k0 += 32) {
        __syncthreads();   // prior frag reads done
        __builtin_amdgcn_global_load_lds(
            (const __attribute__((address_space(1))) void*)ag,
            (__attribute__((address_space(3))) void*)(ldsA + wb), 16, 0, 0);
        __builtin_amdgcn_global_load_lds(
            (const __attribute__((address_space(1))) void*)(ag + (size_t)64 * K_),
            (__attribute__((address_space(3))) void*)(ldsA + 4096 + wb), 16, 0, 0);
        __builtin_amdgcn_global_load_lds(
            (const __attribute__((address_space(1))) void*)bg,
            (__attribute__((address_space(3))) void*)(ldsB + wb), 16, 0, 0);
        __builtin_amdgcn_global_load_lds(
            (const __attribute__((address_space(1))) void*)(bg + (size_t)64 * K_),
            (__attribute__((address_space(3))) void*)(ldsB + 4096 + wb), 16, 0, 0);
        ag += 32;
        bg += 32;
        __syncthreads();   // staged data visible (vmcnt drained at barrier)

        short8 af[4], bfr[4];
#pragma unroll
        for (int i = 0; i < 4; i++)
            af[i] = *(const short8*)&As[(wm + 16 * i + (l & 15)) * 32 + (l >> 4) * 8];
#pragma unroll
        for (int j = 0; j < 4; j++)
            bfr[j] = *(const short8*)&Bs[(wn + 16 * j + (l & 15)) * 32 + (l >> 4) * 8];
#pragma unroll
        for (int i = 0; i < 4; i++)
#pragma unroll
            for (int j = 0; j < 4; j++)
                acc[i][j] = __builtin_amdgcn_mfma_f32_16x16x32_bf16(af[i], bfr[j], acc[i][j], 0, 0, 0);
    }

    // epilogue: C/D layout col = lane&15, row = (lane>>4)*4 + reg  [m89-verified]
    const int cn = bn + wn + (l & 15);
    const int rm = bm + wm + (l >> 4) * 4;
#pragma unroll
    for (int i = 0; i < 4; i++)
#pragma unroll
        for (int j = 0; j < 4; j++)
#pragma unroll
            for (int r = 0; r < 4; r++)
                C[(size_t)(rm + 16 * i + r) * N_ + cn + 16 * j] = acc[i][j][r];
}

// ---------------------------------------------------------------------------
// fp32 -> bf16 straight cast (hidden)
// ---------------------------------------------------------------------------
__global__ __launch_bounds__(256) void cast_bf16(const float* __restrict__ in,
                                                 ushort* __restrict__ outp) {
    const int i = (blockIdx.x * 256 + threadIdx.x) * 4;
    float4 v = *(const float4*)(in + i);
    ushort4 o = {f2bf(v.x), f2bf(v.y), f2bf(v.z), f2bf(v.w)};
    *(ushort4*)(outp + i) = o;
}

// ---------------------------------------------------------------------------
// W[K_][N_] fp32 -> WT[N_][K_] bf16, LDS-tiled (32k x 64n), +1 pad.
// ---------------------------------------------------------------------------
template <int K_, int N_>
__global__ __launch_bounds__(256) void transpose_cast(const float* __restrict__ W,
                                                      ushort* __restrict__ WT) {
    __shared__ float T[32 * 65];
    const int k0 = blockIdx.y * 32;
    const int n0 = blockIdx.x * 64;
    const int x = threadIdx.x & 63;
    const int y = threadIdx.x >> 6;
#pragma unroll
    for (int p = 0; p < 8; p++) {
        const int kk = p * 4 + y;
        T[kk * 65 + x] = W[(size_t)(k0 + kk) * N_ + n0 + x];
    }
    __syncthreads();
#pragma unroll
    for (int q = 0; q < 4; q++) {
        const int nl = q * 16 + (threadIdx.x >> 4);
        const int k2 = (threadIdx.x & 15) * 2;
        ushort2 o = {f2bf(T[k2 * 65 + nl]), f2bf(T[(k2 + 1) * 65 + nl])};
        *(ushort2*)&WT[(size_t)(n0 + nl) * K_ + k0 + k2] = o;
    }
}

// ---------------------------------------------------------------------------
// NeoX RoPE in-place on q (heads 0..31) and k (heads 32..39), fp32 qkv.
// ---------------------------------------------------------------------------
__global__ __launch_bounds__(256) void rope_kernel(const int* __restrict__ pos,
                                                   float* __restrict__ qkv) {
    const int t = blockIdx.x;
    const int head = blockIdx.y * 4 + (threadIdx.x >> 6);
    const int d = threadIdx.x & 63;
    const float p = (float)pos[t];
    const float invf = exp2f(-(float)d * (19.931568569324174f / 64.0f));
    const float f = p * invf;
    const float c = cosf(f), s = sinf(f);
    float* base = qkv + (size_t)t * QKVN + head * HD;
    const float x1 = base[d];
    const float x2 = base[d + 64];
    base[d]      = x1 * c - x2 * s;
    base[d + 64] = x2 * c + x1 * s;
}

// ---------------------------------------------------------------------------
// Flash-style causal GQA attention (fp32 math), templated output dtype.
// ---------------------------------------------------------------------------
#define DOT4(acc, a, b) acc += (a).x*(b).x + (a).y*(b).y + (a).z*(b).z + (a).w*(b).w
#define FMA4(o, p, v) { (o).x += (p)*(v).x; (o).y += (p)*(v).y; (o).z += (p)*(v).z; (o).w += (p)*(v).w; }

template <int BF16OUT>
__global__ __launch_bounds__(256, 2) void flash_attn(const float* __restrict__ qkv,
                                                     void* __restrict__ outp) {
    __shared__ float Qs[64 * 132];
    __shared__ float KVs[32 * 132];
    __shared__ float Ps[64 * 34];

    const int b = blockIdx.x;
    const int half = (b >> 9) & 1;
    const int rest = b & 511;
    const int h = rest >> 4;
    const int qlo = rest & 15;
    const int qi = half ? (31 - qlo) : qlo;
    const int kvh = h >> 2;

    const int tid = threadIdx.x;
    const int tx = tid & 7;
    const int ty = tid >> 3;

    {
        const float* qbase = qkv + (size_t)(qi * 64) * QKVN + h * HD;
#pragma unroll
        for (int r = 0; r < 8; r++) {
            int idx = r * 256 + tid;
            int qrow = idx >> 5;
            int d = (idx & 31) * 4;
            float4 v = *(const float4*)(qbase + (size_t)qrow * QKVN + d);
            v.x *= SCALE; v.y *= SCALE; v.z *= SCALE; v.w *= SCALE;
            *(float4*)(Qs + qrow * 132 + d) = v;
        }
    }

    float m[2], l[2];
    float4 O[2][4];
#pragma unroll
    for (int i = 0; i < 2; i++) {
        m[i] = -INFINITY;
        l[i] = 0.f;
#pragma unroll
        for (int jj = 0; jj < 4; jj++) O[i][jj] = make_float4(0.f, 0.f, 0.f, 0.f);
    }

    const float* kbase = qkv + KV_OFF + kvh * HD;
    const float* vbase = qkv + V_OFF + kvh * HD;
    const int qg0 = qi * 64 + ty;
    const int nst = 2 * qi + 2;

    for (int st = 0; st < nst; st++) {
        __syncthreads();
#pragma unroll
        for (int r = 0; r < 4; r++) {
            int idx = r * 256 + tid;
            int srow = idx >> 5;
            int d = (idx & 31) * 4;
            *(float4*)(KVs + srow * 132 + d) =
                *(const float4*)(kbase + (size_t)(st * 32 + srow) * QKVN + d);
        }
        __syncthreads();

        float S[2][4];
#pragma unroll
        for (int i = 0; i < 2; i++)
#pragma unroll
            for (int j = 0; j < 4; j++) S[i][j] = 0.f;

#pragma unroll 4
        for (int kk = 0; kk < HD; kk += 4) {
            float4 q0 = *(const float4*)(Qs + ty * 132 + kk);
            float4 q1 = *(const float4*)(Qs + (ty + 32) * 132 + kk);
            float4 k0 = *(const float4*)(KVs + tx * 132 + kk);
            float4 k1 = *(const float4*)(KVs + (tx + 8) * 132 + kk);
            float4 k2 = *(const float4*)(KVs + (tx + 16) * 132 + kk);
            float4 k3 = *(const float4*)(KVs + (tx + 24) * 132 + kk);
            DOT4(S[0][0], q0, k0); DOT4(S[0][1], q0, k1);
            DOT4(S[0][2], q0, k2); DOT4(S[0][3], q0, k3);
            DOT4(S[1][0], q1, k0); DOT4(S[1][1], q1, k1);
            DOT4(S[1][2], q1, k2); DOT4(S[1][3], q1, k3);
        }

        const int sg0 = st * 32 + tx;
        float alpha[2];
#pragma unroll
        for (int i = 0; i < 2; i++) {
            const int qg = qg0 + 32 * i;
            float rmax = -INFINITY;
#pragma unroll
            for (int j = 0; j < 4; j++) {
                if (sg0 + 8 * j > qg) S[i][j] = -INFINITY;
                rmax = fmaxf(rmax, S[i][j]);
            }
#pragma unroll
            for (int off = 1; off < 8; off <<= 1)
                rmax = fmaxf(rmax, __shfl_xor(rmax, off));
            const float mnew = fmaxf(m[i], rmax);
            alpha[i] = __expf(m[i] - mnew);
            float rsum = 0.f;
#pragma unroll
            for (int j = 0; j < 4; j++) {
                S[i][j] = __expf(S[i][j] - mnew);
                rsum += S[i][j];
            }
#pragma unroll
            for (int off = 1; off < 8; off <<= 1)
                rsum += __shfl_xor(rsum, off);
            l[i] = l[i] * alpha[i] + rsum;
            m[i] = mnew;
        }

#pragma unroll
        for (int i = 0; i < 2; i++)
#pragma unroll
            for (int j = 0; j < 4; j++)
                Ps[(ty + 32 * i) * 34 + tx + 8 * j] = S[i][j];

        __syncthreads();
#pragma unroll
        for (int r = 0; r < 4; r++) {
            int idx = r * 256 + tid;
            int srow = idx >> 5;
            int d = (idx & 31) * 4;
            *(float4*)(KVs + srow * 132 + d) =
                *(const float4*)(vbase + (size_t)(st * 32 + srow) * QKVN + d);
        }
        __syncthreads();

#pragma unroll
        for (int i = 0; i < 2; i++) {
            const float a = alpha[i];
#pragma unroll
            for (int jj = 0; jj < 4; jj++) {
                O[i][jj].x *= a; O[i][jj].y *= a; O[i][jj].z *= a; O[i][jj].w *= a;
            }
        }
#pragma unroll 4
        for (int s = 0; s < 32; s++) {
            float p0 = Ps[ty * 34 + s];
            float p1 = Ps[(ty + 32) * 34 + s];
            const float* vr = KVs + s * 132 + 4 * tx;
            float4 v0 = *(const float4*)(vr);
            float4 v1 = *(const float4*)(vr + 32);
            float4 v2 = *(const float4*)(vr + 64);
            float4 v3 = *(const float4*)(vr + 96);
            FMA4(O[0][0], p0, v0); FMA4(O[0][1], p0, v1);
            FMA4(O[0][2], p0, v2); FMA4(O[0][3], p0, v3);
            FMA4(O[1][0], p1, v0); FMA4(O[1][1], p1, v1);
            FMA4(O[1][2], p1, v2); FMA4(O[1][3], p1, v3);
        }
    }

#pragma unroll
    for (int i = 0; i < 2; i++) {
        const float inv = 1.0f / l[i];
        const size_t rowoff = (size_t)(qi * 64 + ty + 32 * i) * HDIM + h * HD + 4 * tx;
#pragma unroll
        for (int jj = 0; jj < 4; jj++) {
            float4 w = O[i][jj];
            w.x *= inv; w.y *= inv; w.z *= inv; w.w *= inv;
            if (BF16OUT) {
                ushort4 o = {f2bf(w.x), f2bf(w.y), f2bf(w.z), f2bf(w.w)};
                *(ushort4*)((ushort*)outp + rowoff + 32 * jj) = o;
            } else {
                *(float4*)((float*)outp + rowoff + 32 * jj) = w;
            }
        }
    }
}

// ---------------------------------------------------------------------------
// Fallback fp32 SGEMM (R2 path, used only if workspace is too small)
// ---------------------------------------------------------------------------
template <int N_, int K_>
__global__ __launch_bounds__(256) void sgemm(const float* __restrict__ A,
                                             const float* __restrict__ B,
                                             float* __restrict__ C) {
    __shared__ float As[8][128];
    __shared__ float Bs[8][128];
    const int tid = threadIdx.x;
    const int bm = blockIdx.y * 128;
    const int bn = blockIdx.x * 128;
    const int tx = tid & 15;
    const int ty = tid >> 4;
    const int lm = tid >> 1;
    const int lkq = (tid & 1) * 4;
    const int lr = tid >> 5;
    const int lnq = (tid & 31) * 4;
    float acc[8][8];
#pragma unroll
    for (int i = 0; i < 8; i++)
#pragma unroll
        for (int j = 0; j < 8; j++) acc[i][j] = 0.f;
    const float* Aptr = A + (size_t)(bm + lm) * K_ + lkq;
    const float* Bptr = B + (size_t)lr * N_ + bn + lnq;
    for (int k0 = 0; k0 < K_; k0 += 8) {
        float4 av = *(const float4*)Aptr;
        float4 bv = *(const float4*)Bptr;
        __syncthreads();
        As[lkq + 0][lm] = av.x;
        As[lkq + 1][lm] = av.y;
        As[lkq + 2][lm] = av.z;
        As[lkq + 3][lm] = av.w;
        *(float4*)&Bs[lr][lnq] = bv;
        __syncthreads();
        Aptr += 8;
        Bptr += (size_t)8 * N_;
#pragma unroll
        for (int kk = 0; kk < 8; kk++) {
            float4 a0 = *(const float4*)&As[kk][ty * 4];
            float4 a1 = *(const float4*)&As[kk][64 + ty * 4];
            float4 b0 = *(const float4*)&Bs[kk][tx * 4];
            float4 b1 = *(const float4*)&Bs[kk][64 + tx * 4];
            float a[8] = {a0.x, a0.y, a0.z, a0.w, a1.x, a1.y, a1.z, a1.w};
            float bb[8] = {b0.x, b0.y, b0.z, b0.w, b1.x, b1.y, b1.z, b1.w};
#pragma unroll
            for (int i = 0; i < 8; i++)
#pragma unroll
                for (int j = 0; j < 8; j++) acc[i][j] += a[i] * bb[j];
        }
    }
#pragma unroll
    for (int i = 0; i < 8; i++) {
        int row = bm + ((i < 4) ? (ty * 4 + i) : (64 + ty * 4 + i - 4));
        float4 c0 = {acc[i][0], acc[i][1], acc[i][2], acc[i][3]};
        float4 c1 = {acc[i][4], acc[i][5], acc[i][6], acc[i][7]};
        *(float4*)&C[(size_t)row * N_ + bn + tx * 4] = c0;
        *(float4*)&C[(size_t)row * N_ + bn + 64 + tx * 4] = c1;
    }
}

// ---------------------------------------------------------------------------
extern "C" void kernel_launch(void* const* d_in, const int* in_sizes, int n_in,
                              void* d_out, int out_size, void* d_ws, size_t ws_size,
                              hipStream_t stream) {
    const int*   positions = (const int*)d_in[0];
    const float* hidden    = (const float*)d_in[1];
    const float* Wqkv      = (const float*)d_in[2];
    const float* Wo        = (const float*)d_in[3];
    float* out = (float*)d_out;

    char* ws = (char*)d_ws;
    float*  qkv    = (float*)ws;                               // 50.3 MB fp32
    ushort* hA     = (ushort*)(ws + 50331648);                 // 16.8 MB bf16
    ushort* WqkvT  = (ushort*)(ws + 67108864);                 // 50.3 MB bf16
    ushort* WoT    = (ushort*)(ws + 117440512);                // 33.6 MB bf16
    ushort* attnB  = (ushort*)(ws + 150994944);                // 16.8 MB bf16
    const size_t NEEDED = 167772160;

    if (ws_size >= NEEDED) {
        cast_bf16<<<dim3((T_TOK * HDIM) / 1024), 256, 0, stream>>>(hidden, hA);
        transpose_cast<HDIM, QKVN><<<dim3(QKVN / 64, HDIM / 32), 256, 0, stream>>>(Wqkv, WqkvT);
        transpose_cast<HDIM, HDIM><<<dim3(HDIM / 64, HDIM / 32), 256, 0, stream>>>(Wo, WoT);
        gemm_bf16<QKVN, HDIM><<<dim3(QKVN / 128, T_TOK / 128), 256, 0, stream>>>(hA, WqkvT, qkv);
        rope_kernel<<<dim3(T_TOK, 10), 256, 0, stream>>>(positions, qkv);
        flash_attn<1><<<dim3(1024), 256, 0, stream>>>(qkv, attnB);
        gemm_bf16<HDIM, HDIM><<<dim3(HDIM / 128, T_TOK / 128), 256, 0, stream>>>(attnB, WoT, out);
    } else {
        float* attn = qkv + (size_t)T_TOK * QKVN;
        sgemm<QKVN, HDIM><<<dim3(QKVN / 128, T_TOK / 128), 256, 0, stream>>>(hidden, Wqkv, qkv);
        rope_kernel<<<dim3(T_TOK, 10), 256, 0, stream>>>(positions, qkv);
        flash_attn<0><<<dim3(1024), 256, 0, stream>>>(qkv, attn);
        sgemm<HDIM, HDIM><<<dim3(HDIM / 128, T_TOK / 128), 256, 0, stream>>>(attn, Wo, out);
    }
}

// Round 4
// 686.683 us; speedup vs baseline: 10.7542x; 1.8648x over previous
//
#include <hip/hip_runtime.h>
#include <math.h>

#define T_TOK 2048
#define HDIM  4096
#define QKVN  6144
#define NHEADS 32
#define HD    128
#define KV_OFF 4096
#define V_OFF  5120
#define SCALE 0.08838834764831843f

typedef __attribute__((ext_vector_type(8))) short short8;
typedef __attribute__((ext_vector_type(4))) float f32x4;
typedef __attribute__((ext_vector_type(16))) float f32x16;

__device__ __forceinline__ ushort f2bf(float f) {
    union { float f; unsigned u; } v; v.f = f;
    unsigned r = v.u + 0x7FFFu + ((v.u >> 16) & 1u);   // RNE
    return (ushort)(r >> 16);
}

// ---------------------------------------------------------------------------
// bf16 MFMA GEMM (m97 structure): C[M,N] = A[M,K] * B^T[N,K], C fp32.
// ---------------------------------------------------------------------------
template <int N_, int K_>
__global__ __launch_bounds__(256) void gemm_bf16(const ushort* __restrict__ A,
                                                 const ushort* __restrict__ B,
                                                 float* __restrict__ C) {
    __shared__ ushort As[128 * 32];
    __shared__ ushort Bs[128 * 32];

    const int tid = threadIdx.x;
    const int w = tid >> 6;
    const int l = tid & 63;
    const int bm = blockIdx.y * 128;
    const int bn = blockIdx.x * 128;
    const int wm = (w & 1) * 64;
    const int wn = (w >> 1) * 64;

    f32x4 acc[4][4];
#pragma unroll
    for (int i = 0; i < 4; i++)
#pragma unroll
        for (int j = 0; j < 4; j++) acc[i][j] = (f32x4){0.f, 0.f, 0.f, 0.f};

    const ushort* ag = A + (size_t)(bm + (tid >> 2)) * K_ + (tid & 3) * 8;
    const ushort* bg = B + (size_t)(bn + (tid >> 2)) * K_ + (tid & 3) * 8;

    auto ldsA = (__attribute__((address_space(3))) char*)As;
    auto ldsB = (__attribute__((address_space(3))) char*)Bs;
    const int wb = w * 1024;

    for (int k0 = 0; k0 < K_; k0 += 32) {
        __syncthreads();
        __builtin_amdgcn_global_load_lds(
            (const __attribute__((address_space(1))) void*)ag,
            (__attribute__((address_space(3))) void*)(ldsA + wb), 16, 0, 0);
        __builtin_amdgcn_global_load_lds(
            (const __attribute__((address_space(1))) void*)(ag + (size_t)64 * K_),
            (__attribute__((address_space(3))) void*)(ldsA + 4096 + wb), 16, 0, 0);
        __builtin_amdgcn_global_load_lds(
            (const __attribute__((address_space(1))) void*)bg,
            (__attribute__((address_space(3))) void*)(ldsB + wb), 16, 0, 0);
        __builtin_amdgcn_global_load_lds(
            (const __attribute__((address_space(1))) void*)(bg + (size_t)64 * K_),
            (__attribute__((address_space(3))) void*)(ldsB + 4096 + wb), 16, 0, 0);
        ag += 32;
        bg += 32;
        __syncthreads();

        short8 af[4], bfr[4];
#pragma unroll
        for (int i = 0; i < 4; i++)
            af[i] = *(const short8*)&As[(wm + 16 * i + (l & 15)) * 32 + (l >> 4) * 8];
#pragma unroll
        for (int j = 0; j < 4; j++)
            bfr[j] = *(const short8*)&Bs[(wn + 16 * j + (l & 15)) * 32 + (l >> 4) * 8];
#pragma unroll
        for (int i = 0; i < 4; i++)
#pragma unroll
            for (int j = 0; j < 4; j++)
                acc[i][j] = __builtin_amdgcn_mfma_f32_16x16x32_bf16(af[i], bfr[j], acc[i][j], 0, 0, 0);
    }

    const int cn = bn + wn + (l & 15);
    const int rm = bm + wm + (l >> 4) * 4;
#pragma unroll
    for (int i = 0; i < 4; i++)
#pragma unroll
        for (int j = 0; j < 4; j++)
#pragma unroll
            for (int r = 0; r < 4; r++)
                C[(size_t)(rm + 16 * i + r) * N_ + cn + 16 * j] = acc[i][j][r];
}

// ---------------------------------------------------------------------------
__global__ __launch_bounds__(256) void cast_bf16(const float* __restrict__ in,
                                                 ushort* __restrict__ outp) {
    const int i = (blockIdx.x * 256 + threadIdx.x) * 4;
    float4 v = *(const float4*)(in + i);
    ushort4 o = {f2bf(v.x), f2bf(v.y), f2bf(v.z), f2bf(v.w)};
    *(ushort4*)(outp + i) = o;
}

// ---------------------------------------------------------------------------
template <int K_, int N_>
__global__ __launch_bounds__(256) void transpose_cast(const float* __restrict__ W,
                                                      ushort* __restrict__ WT) {
    __shared__ float T[32 * 65];
    const int k0 = blockIdx.y * 32;
    const int n0 = blockIdx.x * 64;
    const int x = threadIdx.x & 63;
    const int y = threadIdx.x >> 6;
#pragma unroll
    for (int p = 0; p < 8; p++) {
        const int kk = p * 4 + y;
        T[kk * 65 + x] = W[(size_t)(k0 + kk) * N_ + n0 + x];
    }
    __syncthreads();
#pragma unroll
    for (int q = 0; q < 4; q++) {
        const int nl = q * 16 + (threadIdx.x >> 4);
        const int k2 = (threadIdx.x & 15) * 2;
        ushort2 o = {f2bf(T[k2 * 65 + nl]), f2bf(T[(k2 + 1) * 65 + nl])};
        *(ushort2*)&WT[(size_t)(n0 + nl) * K_ + k0 + k2] = o;
    }
}

// ---------------------------------------------------------------------------
// NeoX RoPE fp32 qkv -> bf16 qkB for q (scaled) and k heads. v cols unwritten.
// ---------------------------------------------------------------------------
__global__ __launch_bounds__(256) void rope_cast(const int* __restrict__ pos,
                                                 const float* __restrict__ qkv,
                                                 ushort* __restrict__ qkB) {
    const int t = blockIdx.x;
    const int slot = blockIdx.y * 4 + (threadIdx.x >> 6);   // 0..39
    const int d = threadIdx.x & 63;
    const float p = (float)pos[t];
    const float invf = exp2f(-(float)d * (19.931568569324174f / 64.0f));
    const float f = p * invf;
    const float c = cosf(f), s = sinf(f);
    const float sc = (slot < 32) ? SCALE : 1.0f;
    const float* base = qkv + (size_t)t * QKVN + slot * HD;
    ushort* ob = qkB + (size_t)t * QKVN + slot * HD;
    const float x1 = base[d];
    const float x2 = base[d + 64];
    ob[d]      = f2bf((x1 * c - x2 * s) * sc);
    ob[d + 64] = f2bf((x2 * c + x1 * s) * sc);
}

// ---------------------------------------------------------------------------
// V transpose: qkv fp32 v-part [t][5120 + c] -> Vt bf16 [c][t], c = kvh*128+d.
// ---------------------------------------------------------------------------
__global__ __launch_bounds__(256) void vt_cast(const float* __restrict__ qkv,
                                               ushort* __restrict__ Vt) {
    __shared__ float tile[32][33];
    const int t0 = blockIdx.x * 32;
    const int c0 = blockIdx.y * 32;
    const int tx = threadIdx.x & 31;
    const int ty = threadIdx.x >> 5;   // 0..7
#pragma unroll
    for (int i = 0; i < 4; i++) {
        const int tt = ty + 8 * i;
        tile[tt][tx] = qkv[(size_t)(t0 + tt) * QKVN + V_OFF + c0 + tx];
    }
    __syncthreads();
#pragma unroll
    for (int i = 0; i < 4; i++) {
        const int dd = ty + 8 * i;
        Vt[(size_t)(c0 + dd) * 2048 + t0 + tx] = f2bf(tile[tx][dd]);
    }
}

// ---------------------------------------------------------------------------
// MFMA flash attention. Block = 4 waves x 32 q-rows = 128-q tile, 32-key tiles.
// S^T = K·Q^T via mfma_32x32x16_bf16: lane owns col q = l&31, rows s.
// Q-frags in registers; K/V frags fragment-major in LDS via global_load_lds;
// P stays in registers (half-wave shfl_xor exchange builds the PV B-frag).
// O^T = V^T·P^T accumulated per d-tile; same lane-q as softmax state.
// ---------------------------------------------------------------------------
__global__ __launch_bounds__(256, 2) void flash_attn_mfma(
        const ushort* __restrict__ qkB,
        const ushort* __restrict__ Vt,
        ushort* __restrict__ attnB) {
    __shared__ ushort Kf[8 * 512];   // 8 frags x 1024 B
    __shared__ ushort Vf[8 * 512];

    const int b = blockIdx.x;              // 512
    const int half = b >> 8;
    const int rest = b & 255;
    const int h = rest >> 3;               // 0..31
    const int q8 = rest & 7;
    const int qi = half ? (15 - q8) : q8;  // 0..15, paired for balance
    const int kvh = h >> 2;

    const int tid = threadIdx.x;
    const int w = tid >> 6;
    const int l = tid & 63;
    const int l31 = l & 31;
    const int hf = l >> 5;

    const int qg = qi * 128 + w * 32 + l31;   // this lane's q row

    // Q fragments (B-operand of S^T): lane n=q=l31, k = kt*16 + hf*8 + j
    short8 qf[8];
    {
        const ushort* qrow = qkB + (size_t)qg * QKVN + h * HD + hf * 8;
#pragma unroll
        for (int kt = 0; kt < 8; kt++)
            qf[kt] = *(const short8*)(qrow + kt * 16);
    }

    f32x16 O[4];
#pragma unroll
    for (int dt = 0; dt < 4; dt++)
#pragma unroll
        for (int r = 0; r < 16; r++) O[dt][r] = 0.f;
    float mcur = -INFINITY, lcur = 0.f;

    // staging sources (wave w stages K frags 2w,2w+1 and V frags 2w,2w+1)
    const ushort* kbase = qkB + (size_t)l31 * QKVN + KV_OFF + kvh * HD + (2 * w) * 16 + hf * 8;
    const ushort* vbase = Vt + ((size_t)(kvh * 128 + w * 32 + l31)) * 2048 + hf * 8;

    auto ldsK = (__attribute__((address_space(3))) char*)Kf;
    auto ldsV = (__attribute__((address_space(3))) char*)Vf;

    const int nst = 4 * qi + 4;
    const int mylast = 4 * qi + w;

    for (int st = 0; st < nst; st++) {
        __syncthreads();     // prior frag reads done
        {
            const ushort* kg = kbase + (size_t)st * 32 * QKVN;
            __builtin_amdgcn_global_load_lds(
                (const __attribute__((address_space(1))) void*)kg,
                (__attribute__((address_space(3))) void*)(ldsK + (2 * w) * 1024), 16, 0, 0);
            __builtin_amdgcn_global_load_lds(
                (const __attribute__((address_space(1))) void*)(kg + 16),
                (__attribute__((address_space(3))) void*)(ldsK + (2 * w + 1) * 1024), 16, 0, 0);
            const ushort* vg = vbase + st * 32;
            __builtin_amdgcn_global_load_lds(
                (const __attribute__((address_space(1))) void*)vg,
                (__attribute__((address_space(3))) void*)(ldsV + (2 * w) * 1024), 16, 0, 0);
            __builtin_amdgcn_global_load_lds(
                (const __attribute__((address_space(1))) void*)(vg + 16),
                (__attribute__((address_space(3))) void*)(ldsV + (2 * w + 1) * 1024), 16, 0, 0);
        }
        __syncthreads();     // staged frags visible

        if (st <= mylast) {  // wave-uniform predicate (w-dependent)
            // ---- S^T = K · Q^T ----
            f32x16 S;
#pragma unroll
            for (int r = 0; r < 16; r++) S[r] = 0.f;
#pragma unroll
            for (int kt = 0; kt < 8; kt++) {
                short8 afK = *(const short8*)&Kf[kt * 512 + l * 8];
                S = __builtin_amdgcn_mfma_f32_32x32x16_bf16(afK, qf[kt], S, 0, 0, 0);
            }

            // ---- softmax over s (in-register + one cross-half shuffle) ----
            float p[16];
#pragma unroll
            for (int r = 0; r < 16; r++) p[r] = S[r];
            if (st == mylast) {
                const int sb = st * 32 + 4 * hf;
#pragma unroll
                for (int r = 0; r < 16; r++) {
                    const int sg = sb + (r & 3) + 8 * (r >> 2);
                    if (sg > qg) p[r] = -INFINITY;
                }
            }
            float rmax = p[0];
#pragma unroll
            for (int r = 1; r < 16; r++) rmax = fmaxf(rmax, p[r]);
            rmax = fmaxf(rmax, __shfl_xor(rmax, 32));
            const float mnew = fmaxf(mcur, rmax);
            const float alpha = __expf(mcur - mnew);
            float rsum = 0.f;
#pragma unroll
            for (int r = 0; r < 16; r++) {
                p[r] = __expf(p[r] - mnew);
                rsum += p[r];
            }
            rsum += __shfl_xor(rsum, 32);
            lcur = lcur * alpha + rsum;
            mcur = mnew;

            // ---- rescale O ----
#pragma unroll
            for (int dt = 0; dt < 4; dt++)
#pragma unroll
                for (int r = 0; r < 16; r++) O[dt][r] *= alpha;

            // ---- build PV B-frags: pack bf16 pairs, exchange halves ----
            unsigned pk[8], rk[8];
#pragma unroll
            for (int g = 0; g < 4; g++) {
                pk[2 * g]     = (unsigned)f2bf(p[4 * g])     | ((unsigned)f2bf(p[4 * g + 1]) << 16);
                pk[2 * g + 1] = (unsigned)f2bf(p[4 * g + 2]) | ((unsigned)f2bf(p[4 * g + 3]) << 16);
            }
#pragma unroll
            for (int i = 0; i < 8; i++) rk[i] = (unsigned)__shfl_xor((int)pk[i], 32);

            short8 Pf[2];
#pragma unroll
            for (int kt2 = 0; kt2 < 2; kt2++) {
                const int g = 2 * kt2 + hf;
                union { unsigned u[4]; short8 s; } cvt;
                cvt.u[0] = hf ? rk[2 * g]     : pk[2 * g];
                cvt.u[1] = hf ? rk[2 * g + 1] : pk[2 * g + 1];
                cvt.u[2] = hf ? pk[2 * g]     : rk[2 * g];
                cvt.u[3] = hf ? pk[2 * g + 1] : rk[2 * g + 1];
                Pf[kt2] = cvt.s;
            }

            // ---- O^T += V^T · P^T ----
#pragma unroll
            for (int dt = 0; dt < 4; dt++)
#pragma unroll
                for (int kt2 = 0; kt2 < 2; kt2++) {
                    short8 afV = *(const short8*)&Vf[(dt * 2 + kt2) * 512 + l * 8];
                    O[dt] = __builtin_amdgcn_mfma_f32_32x32x16_bf16(afV, Pf[kt2], O[dt], 0, 0, 0);
                }
        }
    }

    // ---- epilogue: normalize, bf16, store (lane's q row; d from C-layout) ----
    const float inv = 1.0f / lcur;
    ushort* orow = attnB + (size_t)qg * HDIM + h * HD + 4 * hf;
#pragma unroll
    for (int dt = 0; dt < 4; dt++)
#pragma unroll
        for (int rg = 0; rg < 4; rg++) {
            ushort4 o;
            o.x = f2bf(O[dt][4 * rg + 0] * inv);
            o.y = f2bf(O[dt][4 * rg + 1] * inv);
            o.z = f2bf(O[dt][4 * rg + 2] * inv);
            o.w = f2bf(O[dt][4 * rg + 3] * inv);
            *(ushort4*)(orow + dt * 32 + 8 * rg) = o;
        }
}

// ---------------------------------------------------------------------------
// Fallback fp32 path (R2) — used only if workspace is too small.
// ---------------------------------------------------------------------------
__global__ __launch_bounds__(256) void rope_kernel(const int* __restrict__ pos,
                                                   float* __restrict__ qkv) {
    const int t = blockIdx.x;
    const int head = blockIdx.y * 4 + (threadIdx.x >> 6);
    const int d = threadIdx.x & 63;
    const float p = (float)pos[t];
    const float invf = exp2f(-(float)d * (19.931568569324174f / 64.0f));
    const float f = p * invf;
    const float c = cosf(f), s = sinf(f);
    float* base = qkv + (size_t)t * QKVN + head * HD;
    const float x1 = base[d];
    const float x2 = base[d + 64];
    base[d]      = x1 * c - x2 * s;
    base[d + 64] = x2 * c + x1 * s;
}

#define DOT4(acc, a, b) acc += (a).x*(b).x + (a).y*(b).y + (a).z*(b).z + (a).w*(b).w
#define FMA4(o, p, v) { (o).x += (p)*(v).x; (o).y += (p)*(v).y; (o).z += (p)*(v).z; (o).w += (p)*(v).w; }

__global__ __launch_bounds__(256, 2) void flash_attn_f32(const float* __restrict__ qkv,
                                                         float* __restrict__ out) {
    __shared__ float Qs[64 * 132];
    __shared__ float KVs[32 * 132];
    __shared__ float Ps[64 * 34];
    const int b = blockIdx.x;
    const int half = (b >> 9) & 1;
    const int rest = b & 511;
    const int h = rest >> 4;
    const int qlo = rest & 15;
    const int qi = half ? (31 - qlo) : qlo;
    const int kvh = h >> 2;
    const int tid = threadIdx.x;
    const int tx = tid & 7;
    const int ty = tid >> 3;
    {
        const float* qbase = qkv + (size_t)(qi * 64) * QKVN + h * HD;
#pragma unroll
        for (int r = 0; r < 8; r++) {
            int idx = r * 256 + tid;
            int qrow = idx >> 5;
            int d = (idx & 31) * 4;
            float4 v = *(const float4*)(qbase + (size_t)qrow * QKVN + d);
            v.x *= SCALE; v.y *= SCALE; v.z *= SCALE; v.w *= SCALE;
            *(float4*)(Qs + qrow * 132 + d) = v;
        }
    }
    float m[2], lsm[2];
    float4 O[2][4];
#pragma unroll
    for (int i = 0; i < 2; i++) {
        m[i] = -INFINITY; lsm[i] = 0.f;
#pragma unroll
        for (int jj = 0; jj < 4; jj++) O[i][jj] = make_float4(0.f, 0.f, 0.f, 0.f);
    }
    const float* kbase = qkv + KV_OFF + kvh * HD;
    const float* vbase = qkv + V_OFF + kvh * HD;
    const int qg0 = qi * 64 + ty;
    const int nst = 2 * qi + 2;
    for (int st = 0; st < nst; st++) {
        __syncthreads();
#pragma unroll
        for (int r = 0; r < 4; r++) {
            int idx = r * 256 + tid;
            int srow = idx >> 5;
            int d = (idx & 31) * 4;
            *(float4*)(KVs + srow * 132 + d) =
                *(const float4*)(kbase + (size_t)(st * 32 + srow) * QKVN + d);
        }
        __syncthreads();
        float S[2][4];
#pragma unroll
        for (int i = 0; i < 2; i++)
#pragma unroll
            for (int j = 0; j < 4; j++) S[i][j] = 0.f;
#pragma unroll 4
        for (int kk = 0; kk < HD; kk += 4) {
            float4 q0 = *(const float4*)(Qs + ty * 132 + kk);
            float4 q1 = *(const float4*)(Qs + (ty + 32) * 132 + kk);
            float4 k0 = *(const float4*)(KVs + tx * 132 + kk);
            float4 k1 = *(const float4*)(KVs + (tx + 8) * 132 + kk);
            float4 k2 = *(const float4*)(KVs + (tx + 16) * 132 + kk);
            float4 k3 = *(const float4*)(KVs + (tx + 24) * 132 + kk);
            DOT4(S[0][0], q0, k0); DOT4(S[0][1], q0, k1);
            DOT4(S[0][2], q0, k2); DOT4(S[0][3], q0, k3);
            DOT4(S[1][0], q1, k0); DOT4(S[1][1], q1, k1);
            DOT4(S[1][2], q1, k2); DOT4(S[1][3], q1, k3);
        }
        const int sg0 = st * 32 + tx;
        float alpha[2];
#pragma unroll
        for (int i = 0; i < 2; i++) {
            const int qg = qg0 + 32 * i;
            float rmax = -INFINITY;
#pragma unroll
            for (int j = 0; j < 4; j++) {
                if (sg0 + 8 * j > qg) S[i][j] = -INFINITY;
                rmax = fmaxf(rmax, S[i][j]);
            }
#pragma unroll
            for (int off = 1; off < 8; off <<= 1)
                rmax = fmaxf(rmax, __shfl_xor(rmax, off));
            const float mnew = fmaxf(m[i], rmax);
            alpha[i] = __expf(m[i] - mnew);
            float rsum = 0.f;
#pragma unroll
            for (int j = 0; j < 4; j++) {
                S[i][j] = __expf(S[i][j] - mnew);
                rsum += S[i][j];
            }
#pragma unroll
            for (int off = 1; off < 8; off <<= 1)
                rsum += __shfl_xor(rsum, off);
            lsm[i] = lsm[i] * alpha[i] + rsum;
            m[i] = mnew;
        }
#pragma unroll
        for (int i = 0; i < 2; i++)
#pragma unroll
            for (int j = 0; j < 4; j++)
                Ps[(ty + 32 * i) * 34 + tx + 8 * j] = S[i][j];
        __syncthreads();
#pragma unroll
        for (int r = 0; r < 4; r++) {
            int idx = r * 256 + tid;
            int srow = idx >> 5;
            int d = (idx & 31) * 4;
            *(float4*)(KVs + srow * 132 + d) =
                *(const float4*)(vbase + (size_t)(st * 32 + srow) * QKVN + d);
        }
        __syncthreads();
#pragma unroll
        for (int i = 0; i < 2; i++) {
            const float a = alpha[i];
#pragma unroll
            for (int jj = 0; jj < 4; jj++) {
                O[i][jj].x *= a; O[i][jj].y *= a; O[i][jj].z *= a; O[i][jj].w *= a;
            }
        }
#pragma unroll 4
        for (int s = 0; s < 32; s++) {
            float p0 = Ps[ty * 34 + s];
            float p1 = Ps[(ty + 32) * 34 + s];
            const float* vr = KVs + s * 132 + 4 * tx;
            float4 v0 = *(const float4*)(vr);
            float4 v1 = *(const float4*)(vr + 32);
            float4 v2 = *(const float4*)(vr + 64);
            float4 v3 = *(const float4*)(vr + 96);
            FMA4(O[0][0], p0, v0); FMA4(O[0][1], p0, v1);
            FMA4(O[0][2], p0, v2); FMA4(O[0][3], p0, v3);
            FMA4(O[1][0], p1, v0); FMA4(O[1][1], p1, v1);
            FMA4(O[1][2], p1, v2); FMA4(O[1][3], p1, v3);
        }
    }
#pragma unroll
    for (int i = 0; i < 2; i++) {
        const float inv = 1.0f / lsm[i];
        float* orow = out + (size_t)(qi * 64 + ty + 32 * i) * HDIM + h * HD + 4 * tx;
#pragma unroll
        for (int jj = 0; jj < 4; jj++) {
            float4 wv = O[i][jj];
            wv.x *= inv; wv.y *= inv; wv.z *= inv; wv.w *= inv;
            *(float4*)(orow + 32 * jj) = wv;
        }
    }
}

template <int N_, int K_>
__global__ __launch_bounds__(256) void sgemm(const float* __restrict__ A,
                                             const float* __restrict__ B,
                                             float* __restrict__ C) {
    __shared__ float As[8][128];
    __shared__ float Bs[8][128];
    const int tid = threadIdx.x;
    const int bm = blockIdx.y * 128;
    const int bn = blockIdx.x * 128;
    const int tx = tid & 15;
    const int ty = tid >> 4;
    const int lm = tid >> 1;
    const int lkq = (tid & 1) * 4;
    const int lr = tid >> 5;
    const int lnq = (tid & 31) * 4;
    float acc[8][8];
#pragma unroll
    for (int i = 0; i < 8; i++)
#pragma unroll
        for (int j = 0; j < 8; j++) acc[i][j] = 0.f;
    const float* Aptr = A + (size_t)(bm + lm) * K_ + lkq;
    const float* Bptr = B + (size_t)lr * N_ + bn + lnq;
    for (int k0 = 0; k0 < K_; k0 += 8) {
        float4 av = *(const float4*)Aptr;
        float4 bv = *(const float4*)Bptr;
        __syncthreads();
        As[lkq + 0][lm] = av.x;
        As[lkq + 1][lm] = av.y;
        As[lkq + 2][lm] = av.z;
        As[lkq + 3][lm] = av.w;
        *(float4*)&Bs[lr][lnq] = bv;
        __syncthreads();
        Aptr += 8;
        Bptr += (size_t)8 * N_;
#pragma unroll
        for (int kk = 0; kk < 8; kk++) {
            float4 a0 = *(const float4*)&As[kk][ty * 4];
            float4 a1 = *(const float4*)&As[kk][64 + ty * 4];
            float4 b0 = *(const float4*)&Bs[kk][tx * 4];
            float4 b1 = *(const float4*)&Bs[kk][64 + tx * 4];
            float a[8] = {a0.x, a0.y, a0.z, a0.w, a1.x, a1.y, a1.z, a1.w};
            float bb[8] = {b0.x, b0.y, b0.z, b0.w, b1.x, b1.y, b1.z, b1.w};
#pragma unroll
            for (int i = 0; i < 8; i++)
#pragma unroll
                for (int j = 0; j < 8; j++) acc[i][j] += a[i] * bb[j];
        }
    }
#pragma unroll
    for (int i = 0; i < 8; i++) {
        int row = bm + ((i < 4) ? (ty * 4 + i) : (64 + ty * 4 + i - 4));
        float4 c0 = {acc[i][0], acc[i][1], acc[i][2], acc[i][3]};
        float4 c1 = {acc[i][4], acc[i][5], acc[i][6], acc[i][7]};
        *(float4*)&C[(size_t)row * N_ + bn + tx * 4] = c0;
        *(float4*)&C[(size_t)row * N_ + bn + 64 + tx * 4] = c1;
    }
}

// ---------------------------------------------------------------------------
extern "C" void kernel_launch(void* const* d_in, const int* in_sizes, int n_in,
                              void* d_out, int out_size, void* d_ws, size_t ws_size,
                              hipStream_t stream) {
    const int*   positions = (const int*)d_in[0];
    const float* hidden    = (const float*)d_in[1];
    const float* Wqkv      = (const float*)d_in[2];
    const float* Wo        = (const float*)d_in[3];
    float* out = (float*)d_out;

    char* ws = (char*)d_ws;
    // layout (with overlays; qkv fp32 dead after rope_cast/vt_cast):
    float*  qkv   = (float*)ws;                     // [0, 50331648)
    ushort* attnB = (ushort*)ws;                    // overlays dead qkv
    ushort* WqkvT = (ushort*)(ws + 50331648);       // 50331648
    ushort* WoT   = (ushort*)(ws + 100663296);      // 33554432
    ushort* hA    = (ushort*)(ws + 134217728);      // 16777216 (dead after gemm1)
    ushort* qkB   = (ushort*)(ws + 134217728);      // 25165824 overlays hA
    ushort* Vt    = (ushort*)(ws + 159383552);      // 4194304
    const size_t NEEDED = 163577856;

    if (ws_size >= NEEDED) {
        cast_bf16<<<dim3((T_TOK * HDIM) / 1024), 256, 0, stream>>>(hidden, hA);
        transpose_cast<HDIM, QKVN><<<dim3(QKVN / 64, HDIM / 32), 256, 0, stream>>>(Wqkv, WqkvT);
        transpose_cast<HDIM, HDIM><<<dim3(HDIM / 64, HDIM / 32), 256, 0, stream>>>(Wo, WoT);
        gemm_bf16<QKVN, HDIM><<<dim3(QKVN / 128, T_TOK / 128), 256, 0, stream>>>(hA, WqkvT, qkv);
        rope_cast<<<dim3(T_TOK, 10), 256, 0, stream>>>(positions, qkv, qkB);
        vt_cast<<<dim3(T_TOK / 32, 32), 256, 0, stream>>>(qkv, Vt);
        flash_attn_mfma<<<dim3(512), 256, 0, stream>>>(qkB, Vt, attnB);
        gemm_bf16<HDIM, HDIM><<<dim3(HDIM / 128, T_TOK / 128), 256, 0, stream>>>(attnB, WoT, out);
    } else {
        float* attn = qkv + (size_t)T_TOK * QKVN;
        sgemm<QKVN, HDIM><<<dim3(QKVN / 128, T_TOK / 128), 256, 0, stream>>>(hidden, Wqkv, qkv);
        rope_kernel<<<dim3(T_TOK, 10), 256, 0, stream>>>(positions, qkv);
        flash_attn_f32<<<dim3(1024), 256, 0, stream>>>(qkv, attn);
        sgemm<HDIM, HDIM><<<dim3(HDIM / 128, T_TOK / 128), 256, 0, stream>>>(attn, Wo, out);
    }
}